// Round 11
// baseline (218.669 us; speedup 1.0000x reference)
//
#include <hip/hip_runtime.h>
#include <stdint.h>

typedef unsigned short u16;
typedef unsigned int   u32;
typedef __attribute__((ext_vector_type(8))) short bf16x8;   // 8 bf16 = 4 VGPRs
typedef __attribute__((ext_vector_type(4))) float f32x4;    // MFMA 16x16 acc

__device__ __forceinline__ u16 f2b(float f) {
    union { float f; u32 i; } v; v.f = f;
    return (u16)((v.i + 0x7fffu + ((v.i >> 16) & 1u)) >> 16);
}
__device__ __forceinline__ float b2f(u16 u) {
    union { float f; u32 i; } v; v.i = ((u32)u) << 16; return v.f;
}
__device__ __forceinline__ bf16x8 pack8(const float* s) {
    union { bf16x8 v; u16 u[8]; } r;
    #pragma unroll
    for (int i = 0; i < 8; i++) r.u[i] = f2b(s[i]);
    return r.v;
}
// RNE bf16 pack via HW instruction (same rounding as f2b, 4 instrs per 8)
__device__ __forceinline__ bf16x8 pack8_cvt(const float* s) {
    union { bf16x8 v; u32 u[4]; } r;
    #pragma unroll
    for (int i = 0; i < 4; i++)
        asm("v_cvt_pk_bf16_f32 %0, %1, %2"
            : "=v"(r.u[i]) : "v"(s[2 * i]), "v"(s[2 * i + 1]));
    return r.v;
}
__device__ __forceinline__ float softplus_f(float x) {
    return x > 15.f ? x : log1pf(__expf(x));
}

// ---------------------------------------------------------------------------
// prep r24: gates + weight conversion only. The x/y bf16 conversion is gone —
// gemm_qkv now converts A from fp32 during LDS staging (cvt_pk, bit-identical
// RNE), killing the 12 MB xbf/ybf write + read round-trip. Gate blocks:
// 8 tokens/block (32 lanes/token, 8 cols/lane). Blocks 0..3071: gates.
// 3072..3391: weights. lg stores log2(g).
// ---------------------------------------------------------------------------
__global__ __launch_bounds__(256) void prep(
    const float* __restrict__ X, const float* __restrict__ Y,
    const float* __restrict__ gWx, const float* __restrict__ gbx,
    const float* __restrict__ gWy, const float* __restrict__ gby,
    float* __restrict__ goutx, float* __restrict__ lgx,
    float* __restrict__ gouty, float* __restrict__ lgy,
    const float* p0, const float* p1, const float* p2, const float* p3,
    const float* p4, const float* p5, const float* p6, const float* p7,
    const float* p8, const float* p9, u16* __restrict__ wdst)
{
    const int blk = blockIdx.x;
    const int t = threadIdx.x;
    if (blk < 3072) {
        // ---- evidential gates: 8 tokens/block ----
        int tok = blk * 8 + (t >> 5);
        const bool isx = tok < 8192;
        const float* T  = isx ? X : Y;
        const float* gW = isx ? gWx : gWy;
        const float* gb = isx ? gbx : gby;
        float* go = isx ? goutx : gouty;
        float* lg = isx ? lgx : lgy;
        if (!isx) tok -= 8192;
        const float* xp = T + (size_t)tok * 256;
        const int c0 = (t & 31) * 8;
        float tmp[8];
        *(float4*)&tmp[0] = *(const float4*)(xp + c0);
        *(float4*)&tmp[4] = *(const float4*)(xp + c0 + 4);
        float a[4];
        #pragma unroll
        for (int j = 0; j < 4; j++) {
            float4 w0 = *(const float4*)(gW + j * 256 + c0);
            float4 w1 = *(const float4*)(gW + j * 256 + c0 + 4);
            a[j] = tmp[0]*w0.x + tmp[1]*w0.y + tmp[2]*w0.z + tmp[3]*w0.w
                 + tmp[4]*w1.x + tmp[5]*w1.y + tmp[6]*w1.z + tmp[7]*w1.w;
        }
        #pragma unroll
        for (int o = 16; o > 0; o >>= 1) {
            #pragma unroll
            for (int j = 0; j < 4; j++) a[j] += __shfl_xor(a[j], o);
        }
        if ((t & 31) == 0) {
            float mu    = a[0] + gb[0];
            float v     = softplus_f(a[1] + gb[1]) + 1e-6f;
            float alpha = softplus_f(a[2] + gb[2]) + 1.0f + 1e-6f;
            float beta  = softplus_f(a[3] + gb[3]) + 1e-6f;
            float var_ep = beta / (v * (alpha - 1.0f));
            float sig = 1.0f / (1.0f + __expf(-mu));
            float gg = fmaxf(sig * __expf(-2.0f * var_ep), 1e-6f);
            go[tok] = gg;
            lg[tok] = log2f(gg);          // log2 for exp2-folded softmax
        }
    } else {
        // ---- weights fp32 -> bf16 ----
        int g = (blk - 3072) * 256 + t;
        int wsel = g >> 13, off = g & 8191;
        const float* src;
        switch (wsel) {
            case 0: src = p0; break; case 1: src = p1; break;
            case 2: src = p2; break; case 3: src = p3; break;
            case 4: src = p4; break; case 5: src = p5; break;
            case 6: src = p6; break; case 7: src = p7; break;
            case 8: src = p8; break; default: src = p9; break;
        }
        float tmp[8];
        *(float4*)&tmp[0] = *(const float4*)(src + (size_t)off * 8);
        *(float4*)&tmp[4] = *(const float4*)(src + (size_t)off * 8 + 4);
        *(bf16x8*)(wdst + ((size_t)wsel * 65536) + (size_t)off * 8) = pack8(tmp);
    }
}

// ---------------------------------------------------------------------------
// Fused QKV GEMM. r23 = r17 single-buffer structure (the config inside the
// 207.2 best; r22's dbuf was neutral-negative and is reverted), with A
// staged DIRECTLY from fp32 x/y via v_cvt_pk_bf16_f32 (RNE, bit-identical
// to the old prep conversion). A-reads are L3-warm (prep's gate pass just
// touched all of X/Y). W stays bf16 from wbf.
// ---------------------------------------------------------------------------
__global__ __launch_bounds__(256, 2) void gemm_qkv(
    const float* __restrict__ Xf, const float* __restrict__ Yf,
    const u16* __restrict__ Wx, const u16* __restrict__ Wy,
    u16* __restrict__ Qx, u16* __restrict__ Kx, u16* __restrict__ VTx,
    u16* __restrict__ Qy, u16* __restrict__ Ky, u16* __restrict__ VTy)
{
    __shared__ short smem[2 * 128 * 72];
    short* As = smem;
    short* Ws = smem + 128 * 72;
    const int t = threadIdx.x;
    const int id = blockIdx.x;                  // 0..1151
    const int wk = (id & 7) * 144 + (id >> 3);  // bijective (1152 = 8*144)
    const int bn = wk % 6;
    int bm = wk / 6;
    const bool isx = bm < 64;
    const float* Af = isx ? Xf : Yf;
    const u16*   W  = isx ? Wx : Wy;
    u16* Qo  = isx ? Qx : Qy;
    u16* Ko  = isx ? Kx : Ky;
    u16* VTo = isx ? VTx : VTy;
    const int tqsh = isx ? 9 : 10;
    if (!isx) bm -= 64;

    const int w = t >> 6, lane = t & 63, li = lane & 15, quad = lane >> 4;
    const int wm = (w >> 1) * 64, wn = (w & 1) * 64;
    const int sr = t >> 1, scb = (t & 1) * 32;

    f32x4 zero = {0.f, 0.f, 0.f, 0.f};
    f32x4 acc[4][4];
    #pragma unroll
    for (int a = 0; a < 4; a++)
        #pragma unroll
        for (int b = 0; b < 4; b++) acc[a][b] = zero;

    for (int ch = 0; ch < 4; ch++) {
        const int k0 = ch * 64;
        if (ch) __syncthreads();
        {
            const float* Apf = Af + (size_t)(bm * 128 + sr) * 256 + k0 + scb;
            const u16*   Wp  = W + (size_t)(bn * 128 + sr) * 256 + k0 + scb;
            #pragma unroll
            for (int j = 0; j < 4; j++) {
                float tmp[8];
                *(float4*)&tmp[0] = *(const float4*)(Apf + j * 8);
                *(float4*)&tmp[4] = *(const float4*)(Apf + j * 8 + 4);
                *(bf16x8*)&As[sr * 72 + scb + j * 8] = pack8_cvt(tmp);
                *(uint4*)&Ws[sr * 72 + scb + j * 8] = *(const uint4*)(Wp + j * 8);
            }
        }
        __syncthreads();
        #pragma unroll
        for (int c = 0; c < 2; c++) {
            bf16x8 af[4], bf[4];
            #pragma unroll
            for (int mt = 0; mt < 4; mt++)
                af[mt] = *(const bf16x8*)&As[(wm + mt * 16 + li) * 72 + c * 32 + quad * 8];
            #pragma unroll
            for (int nt = 0; nt < 4; nt++)
                bf[nt] = *(const bf16x8*)&Ws[(wn + nt * 16 + li) * 72 + c * 32 + quad * 8];
            #pragma unroll
            for (int mt = 0; mt < 4; mt++)
                #pragma unroll
                for (int nt = 0; nt < 4; nt++)
                    acc[mt][nt] = __builtin_amdgcn_mfma_f32_16x16x32_bf16(
                        af[mt], bf[nt], acc[mt][nt], 0, 0, 0);
        }
    }

    const int sel = bn >> 1;
    if (sel < 2) {
        // ---- Q/K: linearize through LDS, coalesced uint4 stores ----
        u16* Co = (sel == 0) ? Qo : Ko;
        __syncthreads();                       // all fragment LDS reads done
        short* Lin = smem;                     // 128 rows x 136 = 34816 B
        #pragma unroll
        for (int nt = 0; nt < 4; nt++) {
            const int cl = wn + nt * 16 + li;
            #pragma unroll
            for (int mt = 0; mt < 4; mt++) {
                const int rl0 = wm + mt * 16 + quad * 4;
                #pragma unroll
                for (int i = 0; i < 4; i++)
                    Lin[(rl0 + i) * 136 + cl] = (short)f2b(acc[mt][nt][i]);
            }
        }
        __syncthreads();
        const int dl = t >> 1, seg = t & 1;
        const int cb = (bn & 1) * 128 + seg * 64;
        u16* dst = Co + (size_t)(bm * 128 + dl) * 256 + cb;
        #pragma unroll
        for (int k = 0; k < 8; k++)
            *(uint4*)(dst + k * 8) = *(const uint4*)&Lin[dl * 136 + seg * 64 + k * 8];
    } else {
        __syncthreads();
        short* Trans = smem;
        #pragma unroll
        for (int nt = 0; nt < 4; nt++) {
            const int cl = wn + nt * 16 + li;
            #pragma unroll
            for (int mt = 0; mt < 4; mt++) {
                const int rl0 = wm + mt * 16 + quad * 4;
                #pragma unroll
                for (int i = 0; i < 4; i++)
                    Trans[cl * 136 + rl0 + i] = (short)f2b(acc[mt][nt][i]);
            }
        }
        __syncthreads();
        const int dl = t >> 1, seg = t & 1;
        const int col = (bn - 4) * 128 + dl;
        const int h = col >> 6, dd = col & 63;
        const int bz = (bm * 128) >> tqsh;
        const int key0 = (bm * 128) & ((1 << tqsh) - 1);
        u16* dst = VTo + ((((size_t)(bz * 4 + h)) * 64 + dd) << tqsh) + key0 + seg * 64;
        #pragma unroll
        for (int k = 0; k < 8; k++)
            *(uint4*)(dst + k * 8) = *(const uint4*)&Trans[dl * 136 + seg * 64 + k * 8];
    }
}

// ---------------------------------------------------------------------------
// Fused MFMA flash attention. r21 (unchanged — proven best): ONE barrier per
// k-tile via K/V/Lk double buffer, no register hoists, exp2 softmax,
// cvt_pk packing, XCD swizzle, no setprio.
// ---------------------------------------------------------------------------
__global__ __launch_bounds__(256, 3) void attn3(
    const u16* __restrict__ Q1, const u16* __restrict__ K1, const u16* __restrict__ VT1,
    const float* __restrict__ LG1, u16* __restrict__ O1,
    const u16* __restrict__ Q2, const u16* __restrict__ K2, const u16* __restrict__ VT2,
    const float* __restrict__ LG2, u16* __restrict__ O2)
{
    __shared__ short Ks[2][64][72];
    __shared__ short VTs[2][64][72];
    __shared__ short Ps[64][72];
    __shared__ float Lk[2][64];

    const int t = threadIdx.x;
    const int id = blockIdx.x;                 // 0..767
    const int wk = (id & 7) * 96 + (id >> 3);  // bijective (768 = 8*96)
    const int xi = wk % 12;
    const int rest = wk / 12;                  // = h + 4*bz
    const int h = rest & 3;
    const int bz = rest >> 2;
    const bool ph1 = xi < 4;
    const int qtl = ph1 ? xi : xi - 4;
    const u16* Q  = ph1 ? Q1 : Q2;
    const u16* K  = ph1 ? K1 : K2;
    const u16* VT = ph1 ? VT1 : VT2;
    const float* LG = ph1 ? LG1 : LG2;
    u16* O = ph1 ? O1 : O2;
    const int Tq = ph1 ? 512 : 1024;
    const int Tk = ph1 ? 1024 : 512;

    const int w = t >> 6, lane = t & 63, li = lane & 15, quad = lane >> 4;
    const int q0 = qtl * 128;

    bf16x8 qf[2][2];
    #pragma unroll
    for (int s = 0; s < 2; s++) {
        const u16* qp = Q + (size_t)(bz * Tq + q0 + s * 64 + w * 16 + li) * 256 + h * 64 + quad * 8;
        qf[s][0] = *(const bf16x8*)qp;
        qf[s][1] = *(const bf16x8*)(qp + 32);
    }

    float lsum[2] = {0.f, 0.f};
    f32x4 zero = {0.f, 0.f, 0.f, 0.f};
    f32x4 oacc[2][4];
    #pragma unroll
    for (int s = 0; s < 2; s++)
        #pragma unroll
        for (int md = 0; md < 4; md++) oacc[s][md] = zero;

    const int sr = t >> 2, sc = (t & 3) * 16;
    const u16* Kp  = K + (size_t)(bz * Tk + sr) * 256 + h * 64 + sc;
    const u16* VTp = VT + ((size_t)(bz * 4 + h) * 64 + sr) * Tk + sc;
    const float* LGp = LG + (size_t)bz * Tk;

    uint4 pk0, pk1, pv0, pv1;
    float plk;
    pk0 = *(const uint4*)(Kp);
    pk1 = *(const uint4*)(Kp + 8);
    pv0 = *(const uint4*)(VTp);
    pv1 = *(const uint4*)(VTp + 8);
    plk = (t < 64) ? LGp[t] : 0.f;

    const float SCL = 0.18033688f;    // 0.125 * log2(e)

    int cur = 0;
    for (int kt = 0; kt < Tk; kt += 64) {
        *(uint4*)&Ks[cur][sr][sc]       = pk0;
        *(uint4*)&Ks[cur][sr][sc + 8]   = pk1;
        *(uint4*)&VTs[cur][sr][sc]      = pv0;
        *(uint4*)&VTs[cur][sr][sc + 8]  = pv1;
        if (t < 64) Lk[cur][t] = plk;
        __syncthreads();                 // single barrier per tile
        if (kt + 64 < Tk) {
            pk0 = *(const uint4*)(Kp + (size_t)(kt + 64) * 256);
            pk1 = *(const uint4*)(Kp + (size_t)(kt + 64) * 256 + 8);
            pv0 = *(const uint4*)(VTp + kt + 64);
            pv1 = *(const uint4*)(VTp + kt + 64 + 8);
            if (t < 64) plk = LGp[kt + 64 + t];
        }

        #pragma unroll
        for (int s = 0; s < 2; s++) {
            // QK^T
            f32x4 sacc[4] = {zero, zero, zero, zero};
            #pragma unroll
            for (int c = 0; c < 2; c++)
                #pragma unroll
                for (int mt = 0; mt < 4; mt++) {
                    bf16x8 af = *(const bf16x8*)&Ks[cur][mt * 16 + li][c * 32 + quad * 8];
                    sacc[mt] = __builtin_amdgcn_mfma_f32_16x16x32_bf16(af, qf[s][c], sacc[mt], 0, 0, 0);
                }
            // softmax -> Ps (wave-local rows, reused across s)
            #pragma unroll
            for (int mt = 0; mt < 4; mt++) {
                float4 lk4 = *(const float4*)&Lk[cur][mt * 16 + quad * 4];
                float x0 = fmaf(sacc[mt][0], SCL, lk4.x);
                float x1 = fmaf(sacc[mt][1], SCL, lk4.y);
                float x2 = fmaf(sacc[mt][2], SCL, lk4.z);
                float x3 = fmaf(sacc[mt][3], SCL, lk4.w);
                float p0, p1, p2, p3;
                asm("v_exp_f32 %0, %1" : "=v"(p0) : "v"(x0));
                asm("v_exp_f32 %0, %1" : "=v"(p1) : "v"(x1));
                asm("v_exp_f32 %0, %1" : "=v"(p2) : "v"(x2));
                asm("v_exp_f32 %0, %1" : "=v"(p3) : "v"(x3));
                lsum[s] += (p0 + p1) + (p2 + p3);
                u32 lo, hi;
                asm("v_cvt_pk_bf16_f32 %0, %1, %2" : "=v"(lo) : "v"(p0), "v"(p1));
                asm("v_cvt_pk_bf16_f32 %0, %1, %2" : "=v"(hi) : "v"(p2), "v"(p3));
                uint2 st; st.x = lo; st.y = hi;
                *(uint2*)&Ps[w * 16 + li][mt * 16 + quad * 4] = st;
            }
            // PV for this s (fragments loaded fresh per-c: no hoists)
            #pragma unroll
            for (int c = 0; c < 2; c++) {
                bf16x8 pfv = *(const bf16x8*)&Ps[w * 16 + li][c * 32 + quad * 8];
                #pragma unroll
                for (int md = 0; md < 4; md++) {
                    bf16x8 vf = *(const bf16x8*)&VTs[cur][md * 16 + li][c * 32 + quad * 8];
                    oacc[s][md] = __builtin_amdgcn_mfma_f32_16x16x32_bf16(
                        vf, pfv, oacc[s][md], 0, 0, 0);
                }
            }
        }
        cur ^= 1;
    }

    #pragma unroll
    for (int s = 0; s < 2; s++) {
        float l = lsum[s];
        l += __shfl_xor(l, 16);
        l += __shfl_xor(l, 32);
        const float inv = 1.0f / l;
        u16* op = O + (size_t)(bz * Tq + q0 + s * 64 + w * 16 + li) * 256 + h * 64;
        #pragma unroll
        for (int md = 0; md < 4; md++) {
            float o0 = oacc[s][md][0] * inv;
            float o1 = oacc[s][md][1] * inv;
            float o2 = oacc[s][md][2] * inv;
            float o3 = oacc[s][md][3] * inv;
            u32 lo, hi;
            asm("v_cvt_pk_bf16_f32 %0, %1, %2" : "=v"(lo) : "v"(o0), "v"(o1));
            asm("v_cvt_pk_bf16_f32 %0, %1, %2" : "=v"(hi) : "v"(o2), "v"(o3));
            uint2 st; st.x = lo; st.y = hi;
            *(uint2*)(op + md * 16 + quad * 4) = st;
        }
    }
}

// ---------------------------------------------------------------------------
// r18 ffln (unchanged): BK=64, stage-A2-once, 3 blocks/CU via Ws stride 68.
// LDS = 34816 + 16896 + 1024 = 52736 -> 3 blocks/CU.
// ---------------------------------------------------------------------------
__global__ __launch_bounds__(256, 3) void gemm_ffln(
    const u16* __restrict__ Axb, const u16* __restrict__ Ayb,
    const u16* __restrict__ W1x, const u16* __restrict__ W1y,
    const u16* __restrict__ W2x, const u16* __restrict__ W2y,
    const float* __restrict__ fbx, const float* __restrict__ fby,
    const float* __restrict__ Rx, const float* __restrict__ Ry,
    const float* __restrict__ gxv, const float* __restrict__ bxv,
    const float* __restrict__ gyv, const float* __restrict__ byv,
    float* __restrict__ Fx, float* __restrict__ Fy)
{
    __shared__ short Ws[256 * 68];    // 34816 B (BK=64 chunk of W1/W2)
    __shared__ short A2[32 * 264];    // 16896 B (ctx bf16, then LN1 bf16)
    __shared__ float Sred[32][4];
    __shared__ float Ssq[32][4];

    const int t = threadIdx.x;
    int blk = blockIdx.x;
    const bool isx = blk < 256;
    const u16* A  = isx ? Axb : Ayb;
    const u16* W1 = isx ? W1x : W1y;
    const u16* W2 = isx ? W2x : W2y;
    const float* fb    = isx ? fbx : fby;
    const float* RES   = isx ? Rx : Ry;
    const float* gamma = isx ? gxv : gyv;
    const float* beta  = isx ? bxv : byv;
    float* F = isx ? Fx : Fy;
    if (!isx) blk -= 256;
    const int r0 = blk * 32;

    const int w = t >> 6, lane = t & 63, li = lane & 15, quad = lane >> 4;
    const int wn = w * 64;

    // ---- stage ctx A-tile once into A2 (coalesced; first barrier orders) ----
    {
        const int ar = t >> 3;            // 0..31
        const int ac = (t & 7) * 32;      // 0..224
        const u16* Ap = A + (size_t)(r0 + ar) * 256 + ac;
        #pragma unroll
        for (int j = 0; j < 4; j++)
            *(uint4*)&A2[ar * 264 + ac + j * 8] = *(const uint4*)(Ap + j * 8);
    }

    f32x4 zero = {0.f, 0.f, 0.f, 0.f};
    f32x4 acc[2][4];
    #pragma unroll
    for (int a = 0; a < 2; a++)
        #pragma unroll
        for (int b = 0; b < 4; b++) acc[a][b] = zero;

    const int wr0 = t >> 3, wseg = (t & 7) * 8;        // W staging (256x64)

    // ---------------- GEMM1: ctx @ W1^T ----------------
    for (int ch = 0; ch < 4; ch++) {
        const int k0 = ch * 64;
        if (ch) __syncthreads();           // Ws reads of ch-1 done
        #pragma unroll
        for (int jj = 0; jj < 8; jj++) {
            const int row = wr0 + jj * 32;
            *(uint4*)&Ws[row * 68 + wseg] =
                *(const uint4*)(W1 + (size_t)row * 256 + k0 + wseg);
        }
        __syncthreads();                   // Ws ready; orders A2 staging (ch0)
        #pragma unroll
        for (int c = 0; c < 2; c++) {
            bf16x8 af[2], bf[4];
            #pragma unroll
            for (int mt = 0; mt < 2; mt++)
                af[mt] = *(const bf16x8*)&A2[(mt * 16 + li) * 264 + k0 + c * 32 + quad * 8];
            #pragma unroll
            for (int nt = 0; nt < 4; nt++)
                bf[nt] = *(const bf16x8*)&Ws[(wn + nt * 16 + li) * 68 + c * 32 + quad * 8];
            #pragma unroll
            for (int mt = 0; mt < 2; mt++)
                #pragma unroll
                for (int nt = 0; nt < 4; nt++)
                    acc[mt][nt] = __builtin_amdgcn_mfma_f32_16x16x32_bf16(
                        af[mt], bf[nt], acc[mt][nt], 0, 0, 0);
        }
    }

    // per-col constants
    float gv[4], btv[4], fbv[4];
    #pragma unroll
    for (int nt = 0; nt < 4; nt++) {
        const int col = wn + nt * 16 + li;
        gv[nt]  = gamma[col];
        btv[nt] = beta[col];
        fbv[nt] = fb[col];
    }

    // ---------------- epilogue 1: +RES, row stats ----------------
    float psum[2][4], psq[2][4];
    #pragma unroll
    for (int mt = 0; mt < 2; mt++) {
        #pragma unroll
        for (int i = 0; i < 4; i++) { psum[mt][i] = 0.f; psq[mt][i] = 0.f; }
        #pragma unroll
        for (int nt = 0; nt < 4; nt++) {
            const int col = wn + nt * 16 + li;
            #pragma unroll
            for (int i = 0; i < 4; i++) {
                const int row = mt * 16 + quad * 4 + i;
                float v = acc[mt][nt][i] + RES[(size_t)(r0 + row) * 256 + col];
                acc[mt][nt][i] = v;
                psum[mt][i] += v;
                psq[mt][i]  += v * v;
            }
        }
        #pragma unroll
        for (int i = 0; i < 4; i++) {
            #pragma unroll
            for (int off = 1; off < 16; off <<= 1) {
                psum[mt][i] += __shfl_xor(psum[mt][i], off);
                psq[mt][i]  += __shfl_xor(psq[mt][i], off);
            }
        }
    }
    if (li == 0) {
        #pragma unroll
        for (int mt = 0; mt < 2; mt++)
            #pragma unroll
            for (int i = 0; i < 4; i++) {
                Sred[mt * 16 + quad * 4 + i][w] = psum[mt][i];
                Ssq[mt * 16 + quad * 4 + i][w]  = psq[mt][i];
            }
    }
    __syncthreads();   // stats ready; all GEMM1 A2/Ws reads complete

    // ---------------- LN1 -> registers (fp32) + A2 (bf16, overwrite) -------
    #pragma unroll
    for (int mt = 0; mt < 2; mt++) {
        #pragma unroll
        for (int i = 0; i < 4; i++) {
            const int row = mt * 16 + quad * 4 + i;
            float4 s4 = *(const float4*)&Sred[row][0];
            float4 q4 = *(const float4*)&Ssq[row][0];
            float S  = (s4.x + s4.y) + (s4.z + s4.w);
            float S2 = (q4.x + q4.y) + (q4.z + q4.w);
            float mean = S * (1.0f / 256.0f);
            float var  = S2 * (1.0f / 256.0f) - mean * mean;
            float rstd = rsqrtf(var + 1e-5f);
            #pragma unroll
            for (int nt = 0; nt < 4; nt++) {
                const int col = wn + nt * 16 + li;
                float ln = (acc[mt][nt][i] - mean) * rstd * gv[nt] + btv[nt];
                acc[mt][nt][i] = ln;           // residual for LN2
                A2[row * 264 + col] = (short)f2b(ln);
            }
        }
    }

    // ---------------- GEMM2: LN1 @ W2^T ----------------
    f32x4 acc2[2][4];
    #pragma unroll
    for (int a = 0; a < 2; a++)
        #pragma unroll
        for (int b = 0; b < 4; b++) acc2[a][b] = zero;

    for (int ch = 0; ch < 4; ch++) {
        const int k0 = ch * 64;
        __syncthreads();                   // prev Ws reads + LN1 A2 writes joined
        #pragma unroll
        for (int jj = 0; jj < 8; jj++) {
            const int row = wr0 + jj * 32;
            *(uint4*)&Ws[row * 68 + wseg] =
                *(const uint4*)(W2 + (size_t)row * 256 + k0 + wseg);
        }
        __syncthreads();
        #pragma unroll
        for (int c = 0; c < 2; c++) {
            bf16x8 af[2], bf[4];
            #pragma unroll
            for (int mt = 0; mt < 2; mt++)
                af[mt] = *(const bf16x8*)&A2[(mt * 16 + li) * 264 + k0 + c * 32 + quad * 8];
            #pragma unroll
            for (int nt = 0; nt < 4; nt++)
                bf[nt] = *(const bf16x8*)&Ws[(wn + nt * 16 + li) * 68 + c * 32 + quad * 8];
            #pragma unroll
            for (int mt = 0; mt < 2; mt++)
                #pragma unroll
                for (int nt = 0; nt < 4; nt++)
                    acc2[mt][nt] = __builtin_amdgcn_mfma_f32_16x16x32_bf16(
                        af[mt], bf[nt], acc2[mt][nt], 0, 0, 0);
        }
    }

    // ---------------- epilogue 2: silu + residual(LN1), stats ----------------
    #pragma unroll
    for (int mt = 0; mt < 2; mt++) {
        #pragma unroll
        for (int i = 0; i < 4; i++) { psum[mt][i] = 0.f; psq[mt][i] = 0.f; }
        #pragma unroll
        for (int nt = 0; nt < 4; nt++) {
            #pragma unroll
            for (int i = 0; i < 4; i++) {
                float u = acc2[mt][nt][i] + fbv[nt];
                u = u / (1.f + __expf(-u));    // silu
                u += acc[mt][nt][i];           // + LN1 (fp32, registers)
                acc2[mt][nt][i] = u;
                psum[mt][i] += u;
                psq[mt][i]  += u * u;
            }
        }
        #pragma unroll
        for (int i = 0; i < 4; i++) {
            #pragma unroll
            for (int off = 1; off < 16; off <<= 1) {
                psum[mt][i] += __shfl_xor(psum[mt][i], off);
                psq[mt][i]  += __shfl_xor(psq[mt][i], off);
            }
        }
    }
    if (li == 0) {
        #pragma unroll
        for (int mt = 0; mt < 2; mt++)
            #pragma unroll
            for (int i = 0; i < 4; i++) {
                Sred[mt * 16 + quad * 4 + i][w] = psum[mt][i];
                Ssq[mt * 16 + quad * 4 + i][w]  = psq[mt][i];
            }
    }
    __syncthreads();

    // ---------------- LN2 -> final fp32 ----------------
    #pragma unroll
    for (int mt = 0; mt < 2; mt++) {
        #pragma unroll
        for (int i = 0; i < 4; i++) {
            const int row = mt * 16 + quad * 4 + i;
            float4 s4 = *(const float4*)&Sred[row][0];
            float4 q4 = *(const float4*)&Ssq[row][0];
            float S  = (s4.x + s4.y) + (s4.z + s4.w);
            float S2 = (q4.x + q4.y) + (q4.z + q4.w);
            float mean = S * (1.0f / 256.0f);
            float var  = S2 * (1.0f / 256.0f) - mean * mean;
            float rstd = rsqrtf(var + 1e-5f);
            #pragma unroll
            for (int nt = 0; nt < 4; nt++) {
                const int col = wn + nt * 16 + li;
                F[(size_t)(r0 + row) * 256 + col] =
                    (acc2[mt][nt][i] - mean) * rstd * gv[nt] + btv[nt];
            }
        }
    }
}

// ---------------------------------------------------------------------------
extern "C" void kernel_launch(void* const* d_in, const int* in_sizes, int n_in,
                              void* d_out, int out_size, void* d_ws, size_t ws_size,
                              hipStream_t stream)
{
    const float* x = (const float*)d_in[0];
    const float* y = (const float*)d_in[1];
    const int wb = (n_in >= 24) ? 4 : 2;
    const float* Wqx  = (const float*)d_in[wb + 0];
    const float* Wkx  = (const float*)d_in[wb + 1];
    const float* Wvx  = (const float*)d_in[wb + 2];
    const float* Wqy  = (const float*)d_in[wb + 3];
    const float* Wky  = (const float*)d_in[wb + 4];
    const float* Wvy  = (const float*)d_in[wb + 5];
    const float* gWx  = (const float*)d_in[wb + 6];
    const float* gbx  = (const float*)d_in[wb + 7];
    const float* gWy  = (const float*)d_in[wb + 8];
    const float* gby  = (const float*)d_in[wb + 9];
    const float* Wox  = (const float*)d_in[wb + 10];
    const float* Woy  = (const float*)d_in[wb + 11];
    const float* lnxg = (const float*)d_in[wb + 12];
    const float* lnxb = (const float*)d_in[wb + 13];
    const float* lnyg = (const float*)d_in[wb + 14];
    const float* lnyb = (const float*)d_in[wb + 15];
    const float* ffxW = (const float*)d_in[wb + 16];
    const float* ffxb = (const float*)d_in[wb + 17];
    const float* ffyW = (const float*)d_in[wb + 18];
    const float* ffyb = (const float*)d_in[wb + 19];

    // --- workspace layout (~52 MB of 256 MiB; xbf/ybf slots retired) ---
    char* ws = (char*)d_ws;
    float* lgx = (float*)(ws);
    float* lgy = (float*)(ws + 32768);
    u16* wbf   = (u16*)(ws + 98304);                 // 10 x 128 KB
    u16* qb    = (u16*)(ws + 1409024);
    u16* kb    = qb  + (size_t)8192 * 256;
    u16* vtb   = kb  + (size_t)16384 * 256;
    u16* qb2   = vtb + (size_t)16384 * 256;
    u16* kb2   = qb2 + (size_t)16384 * 256;
    u16* vtb2  = kb2 + (size_t)8192 * 256;
    u16* ctxx  = vtb2 + (size_t)8192 * 256;          // attn ctx x (bf16)
    u16* ctxy  = ctxx + (size_t)8192 * 256;          // attn ctx y

    float* out_x2 = (float*)d_out;                   // [16,512,256]
    float* out_y2 = out_x2 + 2097152;                // [16,1024,256]
    float* out_gx = out_x2 + 6291456;
    float* out_gy = out_x2 + 6299648;

    // 1: prep (gates + weight cvt; input cvt eliminated)
    prep<<<3392, 256, 0, stream>>>(
        x, y, gWx, gbx, gWy, gby, out_gx, lgx, out_gy, lgy,
        Wqx, Wkx, Wvx, Wqy, Wky, Wvy, Wox, Woy, ffxW, ffyW, wbf);
    // 2: fused QKV projections (fp32-A staging w/ cvt_pk, XCD-swizzled)
    gemm_qkv<<<dim3(1152), 256, 0, stream>>>(
        x, y, wbf + 0 * 65536, wbf + 3 * 65536,
        qb, kb2, vtb2, qb2, kb, vtb);
    // 3: fused attention -> ctx in ws (QBLK=128, dbuf, 1 barrier/tile)
    attn3<<<dim3(768), 256, 0, stream>>>(
        qb, kb, vtb, lgy, ctxx, qb2, kb2, vtb2, lgx, ctxy);
    // 4: o-proj + res + LN1 + FF(silu) + res + LN2, fully fused (3 blk/CU)
    gemm_ffln<<<768, 256, 0, stream>>>(
        ctxx, ctxy, wbf + 6 * 65536, wbf + 7 * 65536,
        wbf + 8 * 65536, wbf + 9 * 65536,
        ffxb, ffyb, x, y,
        lnxg, lnxb, lnyg, lnyb, out_x2, out_y2);

    (void)in_sizes; (void)out_size; (void)ws_size;
}

// Round 12
// 204.996 us; speedup vs baseline: 1.0667x; 1.0667x over previous
//
#include <hip/hip_runtime.h>
#include <stdint.h>

typedef unsigned short u16;
typedef unsigned int   u32;
typedef __attribute__((ext_vector_type(8))) short bf16x8;   // 8 bf16 = 4 VGPRs
typedef __attribute__((ext_vector_type(4))) float f32x4;    // MFMA 16x16 acc

__device__ __forceinline__ u16 f2b(float f) {
    union { float f; u32 i; } v; v.f = f;
    return (u16)((v.i + 0x7fffu + ((v.i >> 16) & 1u)) >> 16);
}
__device__ __forceinline__ float b2f(u16 u) {
    union { float f; u32 i; } v; v.i = ((u32)u) << 16; return v.f;
}
// RNE bf16 pack via HW instruction (same rounding as f2b, 4 instrs per 8)
__device__ __forceinline__ bf16x8 pack8_cvt(const float* s) {
    union { bf16x8 v; u32 u[4]; } r;
    #pragma unroll
    for (int i = 0; i < 4; i++)
        asm("v_cvt_pk_bf16_f32 %0, %1, %2"
            : "=v"(r.u[i]) : "v"(s[2 * i]), "v"(s[2 * i + 1]));
    return r.v;
}
__device__ __forceinline__ float softplus_f(float x) {
    return x > 15.f ? x : log1pf(__expf(x));
}

// ---------------------------------------------------------------------------
// prep r25 = r15 structure (gate GEMV fused into the convert pass — the
// config inside the 207.2 best; r24's separate-gate + fp32-qkv-staging
// regressed qkv 18->43 us via load->cvt->ds_write serialization) with the
// scalar f2b pack replaced by HW v_cvt_pk_bf16_f32 (bit-identical RNE,
// ~4x fewer VALU ops in the convert blocks).
// Blocks 0..3071: convert+gates. 3072..3391: weights. lg stores log2(g).
// ---------------------------------------------------------------------------
__global__ __launch_bounds__(256) void prep(
    const float* __restrict__ X, const float* __restrict__ Y,
    const float* __restrict__ gWx, const float* __restrict__ gbx,
    const float* __restrict__ gWy, const float* __restrict__ gby,
    float* __restrict__ goutx, float* __restrict__ lgx,
    float* __restrict__ gouty, float* __restrict__ lgy,
    u16* __restrict__ xb, u16* __restrict__ yb,
    const float* p0, const float* p1, const float* p2, const float* p3,
    const float* p4, const float* p5, const float* p6, const float* p7,
    const float* p8, const float* p9, u16* __restrict__ wdst)
{
    const int blk = blockIdx.x;
    const int t = threadIdx.x;
    if (blk < 3072) {
        // ---- x/y fp32 -> bf16 + fused evidential gate ----
        int g = blk * 256 + t;
        const bool isx = g < 262144;          // 1024*256 = 262144 x-groups
        const float* src; u16* dst; size_t off; int tok;
        const float *gW, *gb; float *go, *lg;
        if (isx) {
            src = X; dst = xb; off = (size_t)g * 8; tok = g >> 5;
            gW = gWx; gb = gbx; go = goutx; lg = lgx;
        } else {
            int g2 = g - 262144;
            src = Y; dst = yb; off = (size_t)g2 * 8; tok = g2 >> 5;
            gW = gWy; gb = gby; go = gouty; lg = lgy;
        }
        float tmp[8];
        *(float4*)&tmp[0] = *(const float4*)(src + off);
        *(float4*)&tmp[4] = *(const float4*)(src + off + 4);
        *(bf16x8*)(dst + off) = pack8_cvt(tmp);

        // gate partial dots over this thread's 8 columns
        const int c0 = (t & 31) * 8;          // g ≡ t (mod 32)
        float a[4];
        #pragma unroll
        for (int j = 0; j < 4; j++) {
            float4 w0 = *(const float4*)(gW + j * 256 + c0);
            float4 w1 = *(const float4*)(gW + j * 256 + c0 + 4);
            a[j] = tmp[0]*w0.x + tmp[1]*w0.y + tmp[2]*w0.z + tmp[3]*w0.w
                 + tmp[4]*w1.x + tmp[5]*w1.y + tmp[6]*w1.z + tmp[7]*w1.w;
        }
        #pragma unroll
        for (int o = 16; o > 0; o >>= 1) {
            #pragma unroll
            for (int j = 0; j < 4; j++) a[j] += __shfl_xor(a[j], o);
        }
        if ((t & 31) == 0) {
            float mu    = a[0] + gb[0];
            float v     = softplus_f(a[1] + gb[1]) + 1e-6f;
            float alpha = softplus_f(a[2] + gb[2]) + 1.0f + 1e-6f;
            float beta  = softplus_f(a[3] + gb[3]) + 1e-6f;
            float var_ep = beta / (v * (alpha - 1.0f));
            float sig = 1.0f / (1.0f + __expf(-mu));
            float gg = fmaxf(sig * __expf(-2.0f * var_ep), 1e-6f);
            go[tok] = gg;
            lg[tok] = log2f(gg);          // log2 for exp2-folded softmax
        }
    } else {
        // ---- weights fp32 -> bf16 ----
        int g = (blk - 3072) * 256 + t;
        int wsel = g >> 13, off = g & 8191;
        const float* src;
        switch (wsel) {
            case 0: src = p0; break; case 1: src = p1; break;
            case 2: src = p2; break; case 3: src = p3; break;
            case 4: src = p4; break; case 5: src = p5; break;
            case 6: src = p6; break; case 7: src = p7; break;
            case 8: src = p8; break; default: src = p9; break;
        }
        float tmp[8];
        *(float4*)&tmp[0] = *(const float4*)(src + (size_t)off * 8);
        *(float4*)&tmp[4] = *(const float4*)(src + (size_t)off * 8 + 4);
        *(bf16x8*)(wdst + ((size_t)wsel * 65536) + (size_t)off * 8) = pack8_cvt(tmp);
    }
}

// ---------------------------------------------------------------------------
// Fused QKV GEMM (r17 — the config inside the 207.2 best, fully restored):
// bf16-A staging from xbf/ybf, single LDS buffer, LDS-linearized Q/K
// epilogue, XCD swizzle. r22 dbuf (+1.8us) and r23 fp32-staging (+25us)
// both reverted.
// ---------------------------------------------------------------------------
__global__ __launch_bounds__(256, 2) void gemm_qkv(
    const u16* __restrict__ Axb, const u16* __restrict__ Ayb,
    const u16* __restrict__ Wx, const u16* __restrict__ Wy,
    u16* __restrict__ Qx, u16* __restrict__ Kx, u16* __restrict__ VTx,
    u16* __restrict__ Qy, u16* __restrict__ Ky, u16* __restrict__ VTy)
{
    __shared__ short smem[2 * 128 * 72];
    short* As = smem;
    short* Ws = smem + 128 * 72;
    const int t = threadIdx.x;
    const int id = blockIdx.x;                  // 0..1151
    const int wk = (id & 7) * 144 + (id >> 3);  // bijective (1152 = 8*144)
    const int bn = wk % 6;
    int bm = wk / 6;
    const bool isx = bm < 64;
    const u16* A  = isx ? Axb : Ayb;
    const u16* W  = isx ? Wx : Wy;
    u16* Qo  = isx ? Qx : Qy;
    u16* Ko  = isx ? Kx : Ky;
    u16* VTo = isx ? VTx : VTy;
    const int tqsh = isx ? 9 : 10;
    if (!isx) bm -= 64;

    const int w = t >> 6, lane = t & 63, li = lane & 15, quad = lane >> 4;
    const int wm = (w >> 1) * 64, wn = (w & 1) * 64;
    const int sr = t >> 1, scb = (t & 1) * 32;

    f32x4 zero = {0.f, 0.f, 0.f, 0.f};
    f32x4 acc[4][4];
    #pragma unroll
    for (int a = 0; a < 4; a++)
        #pragma unroll
        for (int b = 0; b < 4; b++) acc[a][b] = zero;

    for (int ch = 0; ch < 4; ch++) {
        const int k0 = ch * 64;
        if (ch) __syncthreads();
        {
            const u16* Ap = A + (size_t)(bm * 128 + sr) * 256 + k0 + scb;
            const u16* Wp = W + (size_t)(bn * 128 + sr) * 256 + k0 + scb;
            #pragma unroll
            for (int j = 0; j < 4; j++) {
                *(uint4*)&As[sr * 72 + scb + j * 8] = *(const uint4*)(Ap + j * 8);
                *(uint4*)&Ws[sr * 72 + scb + j * 8] = *(const uint4*)(Wp + j * 8);
            }
        }
        __syncthreads();
        #pragma unroll
        for (int c = 0; c < 2; c++) {
            bf16x8 af[4], bf[4];
            #pragma unroll
            for (int mt = 0; mt < 4; mt++)
                af[mt] = *(const bf16x8*)&As[(wm + mt * 16 + li) * 72 + c * 32 + quad * 8];
            #pragma unroll
            for (int nt = 0; nt < 4; nt++)
                bf[nt] = *(const bf16x8*)&Ws[(wn + nt * 16 + li) * 72 + c * 32 + quad * 8];
            #pragma unroll
            for (int mt = 0; mt < 4; mt++)
                #pragma unroll
                for (int nt = 0; nt < 4; nt++)
                    acc[mt][nt] = __builtin_amdgcn_mfma_f32_16x16x32_bf16(
                        af[mt], bf[nt], acc[mt][nt], 0, 0, 0);
        }
    }

    const int sel = bn >> 1;
    if (sel < 2) {
        // ---- Q/K: linearize through LDS, coalesced uint4 stores ----
        u16* Co = (sel == 0) ? Qo : Ko;
        __syncthreads();                       // all fragment LDS reads done
        short* Lin = smem;                     // 128 rows x 136 = 34816 B
        #pragma unroll
        for (int nt = 0; nt < 4; nt++) {
            const int cl = wn + nt * 16 + li;
            #pragma unroll
            for (int mt = 0; mt < 4; mt++) {
                const int rl0 = wm + mt * 16 + quad * 4;
                #pragma unroll
                for (int i = 0; i < 4; i++)
                    Lin[(rl0 + i) * 136 + cl] = (short)f2b(acc[mt][nt][i]);
            }
        }
        __syncthreads();
        const int dl = t >> 1, seg = t & 1;
        const int cb = (bn & 1) * 128 + seg * 64;
        u16* dst = Co + (size_t)(bm * 128 + dl) * 256 + cb;
        #pragma unroll
        for (int k = 0; k < 8; k++)
            *(uint4*)(dst + k * 8) = *(const uint4*)&Lin[dl * 136 + seg * 64 + k * 8];
    } else {
        __syncthreads();
        short* Trans = smem;
        #pragma unroll
        for (int nt = 0; nt < 4; nt++) {
            const int cl = wn + nt * 16 + li;
            #pragma unroll
            for (int mt = 0; mt < 4; mt++) {
                const int rl0 = wm + mt * 16 + quad * 4;
                #pragma unroll
                for (int i = 0; i < 4; i++)
                    Trans[cl * 136 + rl0 + i] = (short)f2b(acc[mt][nt][i]);
            }
        }
        __syncthreads();
        const int dl = t >> 1, seg = t & 1;
        const int col = (bn - 4) * 128 + dl;
        const int h = col >> 6, dd = col & 63;
        const int bz = (bm * 128) >> tqsh;
        const int key0 = (bm * 128) & ((1 << tqsh) - 1);
        u16* dst = VTo + ((((size_t)(bz * 4 + h)) * 64 + dd) << tqsh) + key0 + seg * 64;
        #pragma unroll
        for (int k = 0; k < 8; k++)
            *(uint4*)(dst + k * 8) = *(const uint4*)&Trans[dl * 136 + seg * 64 + k * 8];
    }
}

// ---------------------------------------------------------------------------
// Fused MFMA flash attention. r21 (unchanged — proven best): ONE barrier per
// k-tile via K/V/Lk double buffer, no register hoists, exp2 softmax,
// cvt_pk packing, XCD swizzle, no setprio.
// ---------------------------------------------------------------------------
__global__ __launch_bounds__(256, 3) void attn3(
    const u16* __restrict__ Q1, const u16* __restrict__ K1, const u16* __restrict__ VT1,
    const float* __restrict__ LG1, u16* __restrict__ O1,
    const u16* __restrict__ Q2, const u16* __restrict__ K2, const u16* __restrict__ VT2,
    const float* __restrict__ LG2, u16* __restrict__ O2)
{
    __shared__ short Ks[2][64][72];
    __shared__ short VTs[2][64][72];
    __shared__ short Ps[64][72];
    __shared__ float Lk[2][64];

    const int t = threadIdx.x;
    const int id = blockIdx.x;                 // 0..767
    const int wk = (id & 7) * 96 + (id >> 3);  // bijective (768 = 8*96)
    const int xi = wk % 12;
    const int rest = wk / 12;                  // = h + 4*bz
    const int h = rest & 3;
    const int bz = rest >> 2;
    const bool ph1 = xi < 4;
    const int qtl = ph1 ? xi : xi - 4;
    const u16* Q  = ph1 ? Q1 : Q2;
    const u16* K  = ph1 ? K1 : K2;
    const u16* VT = ph1 ? VT1 : VT2;
    const float* LG = ph1 ? LG1 : LG2;
    u16* O = ph1 ? O1 : O2;
    const int Tq = ph1 ? 512 : 1024;
    const int Tk = ph1 ? 1024 : 512;

    const int w = t >> 6, lane = t & 63, li = lane & 15, quad = lane >> 4;
    const int q0 = qtl * 128;

    bf16x8 qf[2][2];
    #pragma unroll
    for (int s = 0; s < 2; s++) {
        const u16* qp = Q + (size_t)(bz * Tq + q0 + s * 64 + w * 16 + li) * 256 + h * 64 + quad * 8;
        qf[s][0] = *(const bf16x8*)qp;
        qf[s][1] = *(const bf16x8*)(qp + 32);
    }

    float lsum[2] = {0.f, 0.f};
    f32x4 zero = {0.f, 0.f, 0.f, 0.f};
    f32x4 oacc[2][4];
    #pragma unroll
    for (int s = 0; s < 2; s++)
        #pragma unroll
        for (int md = 0; md < 4; md++) oacc[s][md] = zero;

    const int sr = t >> 2, sc = (t & 3) * 16;
    const u16* Kp  = K + (size_t)(bz * Tk + sr) * 256 + h * 64 + sc;
    const u16* VTp = VT + ((size_t)(bz * 4 + h) * 64 + sr) * Tk + sc;
    const float* LGp = LG + (size_t)bz * Tk;

    uint4 pk0, pk1, pv0, pv1;
    float plk;
    pk0 = *(const uint4*)(Kp);
    pk1 = *(const uint4*)(Kp + 8);
    pv0 = *(const uint4*)(VTp);
    pv1 = *(const uint4*)(VTp + 8);
    plk = (t < 64) ? LGp[t] : 0.f;

    const float SCL = 0.18033688f;    // 0.125 * log2(e)

    int cur = 0;
    for (int kt = 0; kt < Tk; kt += 64) {
        *(uint4*)&Ks[cur][sr][sc]       = pk0;
        *(uint4*)&Ks[cur][sr][sc + 8]   = pk1;
        *(uint4*)&VTs[cur][sr][sc]      = pv0;
        *(uint4*)&VTs[cur][sr][sc + 8]  = pv1;
        if (t < 64) Lk[cur][t] = plk;
        __syncthreads();                 // single barrier per tile
        if (kt + 64 < Tk) {
            pk0 = *(const uint4*)(Kp + (size_t)(kt + 64) * 256);
            pk1 = *(const uint4*)(Kp + (size_t)(kt + 64) * 256 + 8);
            pv0 = *(const uint4*)(VTp + kt + 64);
            pv1 = *(const uint4*)(VTp + kt + 64 + 8);
            if (t < 64) plk = LGp[kt + 64 + t];
        }

        #pragma unroll
        for (int s = 0; s < 2; s++) {
            // QK^T
            f32x4 sacc[4] = {zero, zero, zero, zero};
            #pragma unroll
            for (int c = 0; c < 2; c++)
                #pragma unroll
                for (int mt = 0; mt < 4; mt++) {
                    bf16x8 af = *(const bf16x8*)&Ks[cur][mt * 16 + li][c * 32 + quad * 8];
                    sacc[mt] = __builtin_amdgcn_mfma_f32_16x16x32_bf16(af, qf[s][c], sacc[mt], 0, 0, 0);
                }
            // softmax -> Ps (wave-local rows, reused across s)
            #pragma unroll
            for (int mt = 0; mt < 4; mt++) {
                float4 lk4 = *(const float4*)&Lk[cur][mt * 16 + quad * 4];
                float x0 = fmaf(sacc[mt][0], SCL, lk4.x);
                float x1 = fmaf(sacc[mt][1], SCL, lk4.y);
                float x2 = fmaf(sacc[mt][2], SCL, lk4.z);
                float x3 = fmaf(sacc[mt][3], SCL, lk4.w);
                float p0, p1, p2, p3;
                asm("v_exp_f32 %0, %1" : "=v"(p0) : "v"(x0));
                asm("v_exp_f32 %0, %1" : "=v"(p1) : "v"(x1));
                asm("v_exp_f32 %0, %1" : "=v"(p2) : "v"(x2));
                asm("v_exp_f32 %0, %1" : "=v"(p3) : "v"(x3));
                lsum[s] += (p0 + p1) + (p2 + p3);
                u32 lo, hi;
                asm("v_cvt_pk_bf16_f32 %0, %1, %2" : "=v"(lo) : "v"(p0), "v"(p1));
                asm("v_cvt_pk_bf16_f32 %0, %1, %2" : "=v"(hi) : "v"(p2), "v"(p3));
                uint2 st; st.x = lo; st.y = hi;
                *(uint2*)&Ps[w * 16 + li][mt * 16 + quad * 4] = st;
            }
            // PV for this s (fragments loaded fresh per-c: no hoists)
            #pragma unroll
            for (int c = 0; c < 2; c++) {
                bf16x8 pfv = *(const bf16x8*)&Ps[w * 16 + li][c * 32 + quad * 8];
                #pragma unroll
                for (int md = 0; md < 4; md++) {
                    bf16x8 vf = *(const bf16x8*)&VTs[cur][md * 16 + li][c * 32 + quad * 8];
                    oacc[s][md] = __builtin_amdgcn_mfma_f32_16x16x32_bf16(
                        vf, pfv, oacc[s][md], 0, 0, 0);
                }
            }
        }
        cur ^= 1;
    }

    #pragma unroll
    for (int s = 0; s < 2; s++) {
        float l = lsum[s];
        l += __shfl_xor(l, 16);
        l += __shfl_xor(l, 32);
        const float inv = 1.0f / l;
        u16* op = O + (size_t)(bz * Tq + q0 + s * 64 + w * 16 + li) * 256 + h * 64;
        #pragma unroll
        for (int md = 0; md < 4; md++) {
            float o0 = oacc[s][md][0] * inv;
            float o1 = oacc[s][md][1] * inv;
            float o2 = oacc[s][md][2] * inv;
            float o3 = oacc[s][md][3] * inv;
            u32 lo, hi;
            asm("v_cvt_pk_bf16_f32 %0, %1, %2" : "=v"(lo) : "v"(o0), "v"(o1));
            asm("v_cvt_pk_bf16_f32 %0, %1, %2" : "=v"(hi) : "v"(o2), "v"(o3));
            uint2 st; st.x = lo; st.y = hi;
            *(uint2*)(op + md * 16 + quad * 4) = st;
        }
    }
}

// ---------------------------------------------------------------------------
// r18 ffln (unchanged): BK=64, stage-A2-once, 3 blocks/CU via Ws stride 68.
// LDS = 34816 + 16896 + 1024 = 52736 -> 3 blocks/CU.
// ---------------------------------------------------------------------------
__global__ __launch_bounds__(256, 3) void gemm_ffln(
    const u16* __restrict__ Axb, const u16* __restrict__ Ayb,
    const u16* __restrict__ W1x, const u16* __restrict__ W1y,
    const u16* __restrict__ W2x, const u16* __restrict__ W2y,
    const float* __restrict__ fbx, const float* __restrict__ fby,
    const float* __restrict__ Rx, const float* __restrict__ Ry,
    const float* __restrict__ gxv, const float* __restrict__ bxv,
    const float* __restrict__ gyv, const float* __restrict__ byv,
    float* __restrict__ Fx, float* __restrict__ Fy)
{
    __shared__ short Ws[256 * 68];    // 34816 B (BK=64 chunk of W1/W2)
    __shared__ short A2[32 * 264];    // 16896 B (ctx bf16, then LN1 bf16)
    __shared__ float Sred[32][4];
    __shared__ float Ssq[32][4];

    const int t = threadIdx.x;
    int blk = blockIdx.x;
    const bool isx = blk < 256;
    const u16* A  = isx ? Axb : Ayb;
    const u16* W1 = isx ? W1x : W1y;
    const u16* W2 = isx ? W2x : W2y;
    const float* fb    = isx ? fbx : fby;
    const float* RES   = isx ? Rx : Ry;
    const float* gamma = isx ? gxv : gyv;
    const float* beta  = isx ? bxv : byv;
    float* F = isx ? Fx : Fy;
    if (!isx) blk -= 256;
    const int r0 = blk * 32;

    const int w = t >> 6, lane = t & 63, li = lane & 15, quad = lane >> 4;
    const int wn = w * 64;

    // ---- stage ctx A-tile once into A2 (coalesced; first barrier orders) ----
    {
        const int ar = t >> 3;            // 0..31
        const int ac = (t & 7) * 32;      // 0..224
        const u16* Ap = A + (size_t)(r0 + ar) * 256 + ac;
        #pragma unroll
        for (int j = 0; j < 4; j++)
            *(uint4*)&A2[ar * 264 + ac + j * 8] = *(const uint4*)(Ap + j * 8);
    }

    f32x4 zero = {0.f, 0.f, 0.f, 0.f};
    f32x4 acc[2][4];
    #pragma unroll
    for (int a = 0; a < 2; a++)
        #pragma unroll
        for (int b = 0; b < 4; b++) acc[a][b] = zero;

    const int wr0 = t >> 3, wseg = (t & 7) * 8;        // W staging (256x64)

    // ---------------- GEMM1: ctx @ W1^T ----------------
    for (int ch = 0; ch < 4; ch++) {
        const int k0 = ch * 64;
        if (ch) __syncthreads();           // Ws reads of ch-1 done
        #pragma unroll
        for (int jj = 0; jj < 8; jj++) {
            const int row = wr0 + jj * 32;
            *(uint4*)&Ws[row * 68 + wseg] =
                *(const uint4*)(W1 + (size_t)row * 256 + k0 + wseg);
        }
        __syncthreads();                   // Ws ready; orders A2 staging (ch0)
        #pragma unroll
        for (int c = 0; c < 2; c++) {
            bf16x8 af[2], bf[4];
            #pragma unroll
            for (int mt = 0; mt < 2; mt++)
                af[mt] = *(const bf16x8*)&A2[(mt * 16 + li) * 264 + k0 + c * 32 + quad * 8];
            #pragma unroll
            for (int nt = 0; nt < 4; nt++)
                bf[nt] = *(const bf16x8*)&Ws[(wn + nt * 16 + li) * 68 + c * 32 + quad * 8];
            #pragma unroll
            for (int mt = 0; mt < 2; mt++)
                #pragma unroll
                for (int nt = 0; nt < 4; nt++)
                    acc[mt][nt] = __builtin_amdgcn_mfma_f32_16x16x32_bf16(
                        af[mt], bf[nt], acc[mt][nt], 0, 0, 0);
        }
    }

    // per-col constants
    float gv[4], btv[4], fbv[4];
    #pragma unroll
    for (int nt = 0; nt < 4; nt++) {
        const int col = wn + nt * 16 + li;
        gv[nt]  = gamma[col];
        btv[nt] = beta[col];
        fbv[nt] = fb[col];
    }

    // ---------------- epilogue 1: +RES, row stats ----------------
    float psum[2][4], psq[2][4];
    #pragma unroll
    for (int mt = 0; mt < 2; mt++) {
        #pragma unroll
        for (int i = 0; i < 4; i++) { psum[mt][i] = 0.f; psq[mt][i] = 0.f; }
        #pragma unroll
        for (int nt = 0; nt < 4; nt++) {
            const int col = wn + nt * 16 + li;
            #pragma unroll
            for (int i = 0; i < 4; i++) {
                const int row = mt * 16 + quad * 4 + i;
                float v = acc[mt][nt][i] + RES[(size_t)(r0 + row) * 256 + col];
                acc[mt][nt][i] = v;
                psum[mt][i] += v;
                psq[mt][i]  += v * v;
            }
        }
        #pragma unroll
        for (int i = 0; i < 4; i++) {
            #pragma unroll
            for (int off = 1; off < 16; off <<= 1) {
                psum[mt][i] += __shfl_xor(psum[mt][i], off);
                psq[mt][i]  += __shfl_xor(psq[mt][i], off);
            }
        }
    }
    if (li == 0) {
        #pragma unroll
        for (int mt = 0; mt < 2; mt++)
            #pragma unroll
            for (int i = 0; i < 4; i++) {
                Sred[mt * 16 + quad * 4 + i][w] = psum[mt][i];
                Ssq[mt * 16 + quad * 4 + i][w]  = psq[mt][i];
            }
    }
    __syncthreads();   // stats ready; all GEMM1 A2/Ws reads complete

    // ---------------- LN1 -> registers (fp32) + A2 (bf16, overwrite) -------
    #pragma unroll
    for (int mt = 0; mt < 2; mt++) {
        #pragma unroll
        for (int i = 0; i < 4; i++) {
            const int row = mt * 16 + quad * 4 + i;
            float4 s4 = *(const float4*)&Sred[row][0];
            float4 q4 = *(const float4*)&Ssq[row][0];
            float S  = (s4.x + s4.y) + (s4.z + s4.w);
            float S2 = (q4.x + q4.y) + (q4.z + q4.w);
            float mean = S * (1.0f / 256.0f);
            float var  = S2 * (1.0f / 256.0f) - mean * mean;
            float rstd = rsqrtf(var + 1e-5f);
            #pragma unroll
            for (int nt = 0; nt < 4; nt++) {
                const int col = wn + nt * 16 + li;
                float ln = (acc[mt][nt][i] - mean) * rstd * gv[nt] + btv[nt];
                acc[mt][nt][i] = ln;           // residual for LN2
                A2[row * 264 + col] = (short)f2b(ln);
            }
        }
    }

    // ---------------- GEMM2: LN1 @ W2^T ----------------
    f32x4 acc2[2][4];
    #pragma unroll
    for (int a = 0; a < 2; a++)
        #pragma unroll
        for (int b = 0; b < 4; b++) acc2[a][b] = zero;

    for (int ch = 0; ch < 4; ch++) {
        const int k0 = ch * 64;
        __syncthreads();                   // prev Ws reads + LN1 A2 writes joined
        #pragma unroll
        for (int jj = 0; jj < 8; jj++) {
            const int row = wr0 + jj * 32;
            *(uint4*)&Ws[row * 68 + wseg] =
                *(const uint4*)(W2 + (size_t)row * 256 + k0 + wseg);
        }
        __syncthreads();
        #pragma unroll
        for (int c = 0; c < 2; c++) {
            bf16x8 af[2], bf[4];
            #pragma unroll
            for (int mt = 0; mt < 2; mt++)
                af[mt] = *(const bf16x8*)&A2[(mt * 16 + li) * 264 + k0 + c * 32 + quad * 8];
            #pragma unroll
            for (int nt = 0; nt < 4; nt++)
                bf[nt] = *(const bf16x8*)&Ws[(wn + nt * 16 + li) * 68 + c * 32 + quad * 8];
            #pragma unroll
            for (int mt = 0; mt < 2; mt++)
                #pragma unroll
                for (int nt = 0; nt < 4; nt++)
                    acc2[mt][nt] = __builtin_amdgcn_mfma_f32_16x16x32_bf16(
                        af[mt], bf[nt], acc2[mt][nt], 0, 0, 0);
        }
    }

    // ---------------- epilogue 2: silu + residual(LN1), stats ----------------
    #pragma unroll
    for (int mt = 0; mt < 2; mt++) {
        #pragma unroll
        for (int i = 0; i < 4; i++) { psum[mt][i] = 0.f; psq[mt][i] = 0.f; }
        #pragma unroll
        for (int nt = 0; nt < 4; nt++) {
            #pragma unroll
            for (int i = 0; i < 4; i++) {
                float u = acc2[mt][nt][i] + fbv[nt];
                u = u / (1.f + __expf(-u));    // silu
                u += acc[mt][nt][i];           // + LN1 (fp32, registers)
                acc2[mt][nt][i] = u;
                psum[mt][i] += u;
                psq[mt][i]  += u * u;
            }
        }
        #pragma unroll
        for (int i = 0; i < 4; i++) {
            #pragma unroll
            for (int off = 1; off < 16; off <<= 1) {
                psum[mt][i] += __shfl_xor(psum[mt][i], off);
                psq[mt][i]  += __shfl_xor(psq[mt][i], off);
            }
        }
    }
    if (li == 0) {
        #pragma unroll
        for (int mt = 0; mt < 2; mt++)
            #pragma unroll
            for (int i = 0; i < 4; i++) {
                Sred[mt * 16 + quad * 4 + i][w] = psum[mt][i];
                Ssq[mt * 16 + quad * 4 + i][w]  = psq[mt][i];
            }
    }
    __syncthreads();

    // ---------------- LN2 -> final fp32 ----------------
    #pragma unroll
    for (int mt = 0; mt < 2; mt++) {
        #pragma unroll
        for (int i = 0; i < 4; i++) {
            const int row = mt * 16 + quad * 4 + i;
            float4 s4 = *(const float4*)&Sred[row][0];
            float4 q4 = *(const float4*)&Ssq[row][0];
            float S  = (s4.x + s4.y) + (s4.z + s4.w);
            float S2 = (q4.x + q4.y) + (q4.z + q4.w);
            float mean = S * (1.0f / 256.0f);
            float var  = S2 * (1.0f / 256.0f) - mean * mean;
            float rstd = rsqrtf(var + 1e-5f);
            #pragma unroll
            for (int nt = 0; nt < 4; nt++) {
                const int col = wn + nt * 16 + li;
                F[(size_t)(r0 + row) * 256 + col] =
                    (acc2[mt][nt][i] - mean) * rstd * gv[nt] + btv[nt];
            }
        }
    }
}

// ---------------------------------------------------------------------------
extern "C" void kernel_launch(void* const* d_in, const int* in_sizes, int n_in,
                              void* d_out, int out_size, void* d_ws, size_t ws_size,
                              hipStream_t stream)
{
    const float* x = (const float*)d_in[0];
    const float* y = (const float*)d_in[1];
    const int wb = (n_in >= 24) ? 4 : 2;
    const float* Wqx  = (const float*)d_in[wb + 0];
    const float* Wkx  = (const float*)d_in[wb + 1];
    const float* Wvx  = (const float*)d_in[wb + 2];
    const float* Wqy  = (const float*)d_in[wb + 3];
    const float* Wky  = (const float*)d_in[wb + 4];
    const float* Wvy  = (const float*)d_in[wb + 5];
    const float* gWx  = (const float*)d_in[wb + 6];
    const float* gbx  = (const float*)d_in[wb + 7];
    const float* gWy  = (const float*)d_in[wb + 8];
    const float* gby  = (const float*)d_in[wb + 9];
    const float* Wox  = (const float*)d_in[wb + 10];
    const float* Woy  = (const float*)d_in[wb + 11];
    const float* lnxg = (const float*)d_in[wb + 12];
    const float* lnxb = (const float*)d_in[wb + 13];
    const float* lnyg = (const float*)d_in[wb + 14];
    const float* lnyb = (const float*)d_in[wb + 15];
    const float* ffxW = (const float*)d_in[wb + 16];
    const float* ffxb = (const float*)d_in[wb + 17];
    const float* ffyW = (const float*)d_in[wb + 18];
    const float* ffyb = (const float*)d_in[wb + 19];

    // --- workspace layout (~64 MB of 256 MiB) ---
    char* ws = (char*)d_ws;
    float* lgx = (float*)(ws);
    float* lgy = (float*)(ws + 32768);
    u16* wbf   = (u16*)(ws + 98304);                 // 10 x 128 KB
    u16* xbf   = (u16*)(ws + 1409024);               // 4 MB
    u16* ybf   = xbf + (size_t)8192 * 256;
    u16* qb    = ybf + (size_t)16384 * 256;
    u16* kb    = qb  + (size_t)8192 * 256;
    u16* vtb   = kb  + (size_t)16384 * 256;
    u16* qb2   = vtb + (size_t)16384 * 256;
    u16* kb2   = qb2 + (size_t)16384 * 256;
    u16* vtb2  = kb2 + (size_t)8192 * 256;
    u16* ctxx  = vtb2 + (size_t)8192 * 256;          // attn ctx x (bf16)
    u16* ctxy  = ctxx + (size_t)8192 * 256;          // attn ctx y

    float* out_x2 = (float*)d_out;                   // [16,512,256]
    float* out_y2 = out_x2 + 2097152;                // [16,1024,256]
    float* out_gx = out_x2 + 6291456;
    float* out_gy = out_x2 + 6299648;

    // 1: prep (fused gates+input cvt, weight cvt; cvt_pk packing)
    prep<<<3392, 256, 0, stream>>>(
        x, y, gWx, gbx, gWy, gby, out_gx, lgx, out_gy, lgy,
        xbf, ybf,
        Wqx, Wkx, Wvx, Wqy, Wky, Wvy, Wox, Woy, ffxW, ffyW, wbf);
    // 2: fused QKV projections (r17: bf16-A, single-buffer, XCD-swizzled)
    gemm_qkv<<<dim3(1152), 256, 0, stream>>>(
        xbf, ybf, wbf + 0 * 65536, wbf + 3 * 65536,
        qb, kb2, vtb2, qb2, kb, vtb);
    // 3: fused attention -> ctx in ws (QBLK=128, dbuf, 1 barrier/tile)
    attn3<<<dim3(768), 256, 0, stream>>>(
        qb, kb, vtb, lgy, ctxx, qb2, kb2, vtb2, lgx, ctxy);
    // 4: o-proj + res + LN1 + FF(silu) + res + LN2, fully fused (3 blk/CU)
    gemm_ffln<<<768, 256, 0, stream>>>(
        ctxx, ctxy, wbf + 6 * 65536, wbf + 7 * 65536,
        wbf + 8 * 65536, wbf + 9 * 65536,
        ffxb, ffyb, x, y,
        lnxg, lnxb, lnyg, lnyb, out_x2, out_y2);

    (void)in_sizes; (void)out_size; (void)ws_size;
}